// Round 5
// baseline (3164.041 us; speedup 1.0000x reference)
//
#include <hip/hip_runtime.h>
#include <math.h>

#define HID 64
#define UH_LEN 15
#define N_INC 4

#define TWO_PI_365 0.0172142063f
#define TWO_PI_366 0.0171671554f
#define H24_PI     7.63943727f

typedef short short8 __attribute__((ext_vector_type(8)));
typedef float f32x4  __attribute__((ext_vector_type(4)));

__device__ __forceinline__ float frcp(float x){ return __builtin_amdgcn_rcpf(x); }
__device__ __forceinline__ float sigf(float x){ return frcp(1.0f + __expf(-x)); }
__device__ __forceinline__ float tanhfast(float x){ return 1.0f - 2.0f*frcp(__expf(2.0f*x)+1.0f); }

__device__ __forceinline__ unsigned short f2bf(float f){
    unsigned int u = __float_as_uint(f);
    u += 0x7FFF + ((u >> 16) & 1);
    return (unsigned short)(u >> 16);
}
__device__ __forceinline__ float bf2f(unsigned short h){
    return __uint_as_float(((unsigned int)h) << 16);
}

__device__ const float PLO[30] = {0.5f,0.7f,-2.0f,0.5f,0.05f,0.03f,0.0f,0.1f,0.02f,0.05f,0.0f,
                                  10.0f,5.0f,10.0f,10.0f,5.0f,0.1f,0.001f,0.01f,5.0f,1.0f,0.0f,
                                  0.0f,0.0f,0.0f,0.0f,0.0f,0.0f,1.0f,0.5f};
__device__ const float PHI[30] = {2.0f,1.4f,2.0f,2.0f,0.49f,0.19f,1.0f,1.0f,0.3f,0.5f,0.3f,
                                  300.0f,150.0f,500.0f,1000.0f,400.0f,0.75f,0.05f,0.35f,350.0f,5.0f,0.8f,
                                  0.1f,0.4f,0.2f,0.5f,0.4f,1.0f,6.0f,5.0f};
__device__ const float LOGT[15] = {0.0f,0.69314718f,1.09861229f,1.38629436f,1.60943791f,
                                   1.79175947f,1.94591015f,2.07944154f,2.19722458f,2.30258509f,
                                   2.39789527f,2.48490665f,2.56494936f,2.63905733f,2.70805020f};

__global__ void zero_kernel(float* __restrict__ p, int cnt){
    int i = blockIdx.x*256 + threadIdx.x;
    if (i < cnt) p[i] = 0.0f;
}

// ---------------------------------------------------------------------------
// MFMA LSTM, M=32: block = 4 waves = 32 units (2 row-tiles of 16).
// Wave wv owns hidden slice [16wv,16wv+16); col-tiles {wv,wv+4,wv+8,wv+12}.
// Weight B-frags in 48 VGPRs. h bf16 double-buffered in LDS (swizzled).
// x-part MFMAs (no LDS dep) issue before h-dependent MFMAs.
// ---------------------------------------------------------------------------
__global__ __launch_bounds__(256, 1) void lstm_kernel(
    const float* __restrict__ x_dyn, const float* __restrict__ x_static,
    const float* __restrict__ Wih, const float* __restrict__ Whh,
    const float* __restrict__ b_lstm, const float* __restrict__ Ws,
    const float* __restrict__ bs, const float* __restrict__ Wout,
    const float* __restrict__ bout, float* __restrict__ params,
    int N, int T, int DSTAT)
{
    __shared__ unsigned short h_lds[2][32*64];   // 8 KiB
    __shared__ float s_sh[32*64];                // 8 KiB

    const int tid = threadIdx.x;
    const int wv  = tid >> 6;
    const int ln  = tid & 63;
    const int q   = ln >> 4;
    const int r16 = ln & 15;
    const int u0  = blockIdx.x * 32;

    short8 wf[4][3];
    float  bias[4];
    #pragma unroll
    for (int g = 0; g < 4; ++g) {
        const int n = 64*g + 16*wv + r16;
        bias[g] = b_lstm[n];
        #pragma unroll
        for (int kb = 0; kb < 3; ++kb) {
            short8 w;
            #pragma unroll
            for (int e = 0; e < 8; ++e) {
                int k = 32*kb + 8*q + e;
                float v = 0.0f;
                if (k < 64)      v = Whh[n*64 + k];
                else if (k < 72) v = Wih[n*8 + (k - 64)];
                w[e] = (short)f2bf(v);
            }
            wf[g][kb] = w;
        }
    }

    for (int i = tid; i < 2*32*64; i += 256) ((unsigned short*)h_lds)[i] = 0;
    __syncthreads();

    float c[2][4] = {{0.f,0.f,0.f,0.f},{0.f,0.f,0.f,0.f}};

    const int uxA = min(u0 + r16,      N-1);
    const int uxB = min(u0 + 16 + r16, N-1);
    float xfA[8], xfB[8];
    if (q == 0) {
        const float* pA = x_dyn + (size_t)uxA * T * 8;
        const float* pB = x_dyn + (size_t)uxB * T * 8;
        #pragma unroll
        for (int e = 0; e < 8; ++e) { xfA[e] = pA[e]; xfB[e] = pB[e]; }
    }

    const int jj   = 16*wv + r16;
    const int swz0 = (q       ^ (r16 & 7)) << 3;
    const int swz1 = ((q + 4) ^ (r16 & 7)) << 3;
    const int rdA  = r16*64;
    const int rdB  = (16 + r16)*64;

    for (int t = 0; t < T; ++t) {
        short8 a2A, a2B;
        #pragma unroll
        for (int e = 0; e < 8; ++e) {
            a2A[e] = (q == 0) ? (short)f2bf(xfA[e]) : (short)0;
            a2B[e] = (q == 0) ? (short)f2bf(xfB[e]) : (short)0;
        }

        const int rb = t & 1;
        short8 a0A = *(const short8*)&h_lds[rb][rdA + swz0];
        short8 a1A = *(const short8*)&h_lds[rb][rdA + swz1];
        short8 a0B = *(const short8*)&h_lds[rb][rdB + swz0];
        short8 a1B = *(const short8*)&h_lds[rb][rdB + swz1];

        if (q == 0 && t + 1 < T) {
            const float* pA = x_dyn + ((size_t)uxA * T + (t+1)) * 8;
            const float* pB = x_dyn + ((size_t)uxB * T + (t+1)) * 8;
            #pragma unroll
            for (int e = 0; e < 8; ++e) { xfA[e] = pA[e]; xfB[e] = pB[e]; }
        }

        f32x4 acc[2][4];
        #pragma unroll
        for (int g = 0; g < 4; ++g) {
            f32x4 a; a[0]=bias[g]; a[1]=bias[g]; a[2]=bias[g]; a[3]=bias[g];
            acc[0][g] = __builtin_amdgcn_mfma_f32_16x16x32_bf16(a2A, wf[g][2], a, 0, 0, 0);
            acc[1][g] = __builtin_amdgcn_mfma_f32_16x16x32_bf16(a2B, wf[g][2], a, 0, 0, 0);
        }
        #pragma unroll
        for (int g = 0; g < 4; ++g) {
            acc[0][g] = __builtin_amdgcn_mfma_f32_16x16x32_bf16(a0A, wf[g][0], acc[0][g], 0, 0, 0);
            acc[0][g] = __builtin_amdgcn_mfma_f32_16x16x32_bf16(a1A, wf[g][1], acc[0][g], 0, 0, 0);
            acc[1][g] = __builtin_amdgcn_mfma_f32_16x16x32_bf16(a0B, wf[g][0], acc[1][g], 0, 0, 0);
            acc[1][g] = __builtin_amdgcn_mfma_f32_16x16x32_bf16(a1B, wf[g][1], acc[1][g], 0, 0, 0);
        }

        const int wb = rb ^ 1;
        #pragma unroll
        for (int rt = 0; rt < 2; ++rt) {
            #pragma unroll
            for (int r = 0; r < 4; ++r) {
                float iv = sigf(acc[rt][0][r]);
                float fv = sigf(acc[rt][1][r]);
                float gv = tanhfast(acc[rt][2][r]);
                float ov = sigf(acc[rt][3][r]);
                c[rt][r] = fv*c[rt][r] + iv*gv;
                float hv = ov*tanhfast(c[rt][r]);
                int u = 16*rt + 4*q + r;
                h_lds[wb][u*64 + (((jj>>3) ^ (u&7))<<3) + (jj&7)] = f2bf(hv);
            }
        }
        __syncthreads();
    }

    const int fb = T & 1;
    for (int uu = 0; uu < 8; ++uu) {
        int ul = wv*8 + uu;
        int u  = min(u0 + ul, N-1);
        float a = bs[ln];
        for (int k = 0; k < DSTAT; ++k)
            a = fmaf(x_static[(size_t)u*DSTAT + k], Ws[ln*DSTAT + k], a);
        s_sh[ul*64 + ln] = tanhfast(a);
    }
    if (ln < 30) {
        for (int uu = 0; uu < 8; ++uu) {
            int ul = wv*8 + uu;
            int unit = u0 + ul;
            if (unit < N) {
                float raw = bout[ln];
                #pragma unroll 8
                for (int m = 0; m < 64; ++m) {
                    float hm = bf2f(h_lds[fb][ul*64 + (((m>>3) ^ (ul&7))<<3) + (m&7)]);
                    float sm = s_sh[ul*64 + m];
                    raw = fmaf(hm, Wout[ln*128 + m],      raw);
                    raw = fmaf(sm, Wout[ln*128 + 64 + m], raw);
                }
                float g = sigf(raw);
                params[ln*N + unit] = PLO[ln] + g*(PHI[ln] - PLO[ln]);
            }
        }
    }
}

// ---------------------------------------------------------------------------
// Physics: Snow17 + SAC-SMA serial chain, U units per thread (ILP-U fills
// the ~80% dependency-stall slots of a single latency-bound wave).
// All per-unit state in [U] arrays, fully unrolled (static indices only).
// ---------------------------------------------------------------------------
template<int U, bool SPLIT>
__global__ __launch_bounds__(64, 1) void physics_kernel(
    const float* __restrict__ prcp, const float* __restrict__ tavg,
    const int*   __restrict__ doy,  const float* __restrict__ elev_m,
    const float* __restrict__ lat_rad, const float* __restrict__ area_w,
    const int*   __restrict__ basin_idx, const float* __restrict__ P,
    float* __restrict__ surfA, float* __restrict__ baseA,
    float* __restrict__ out, int N, int T, int B)
{
    const int g  = blockIdx.x*64 + threadIdx.x;
    const int n0 = U*g;
    if (n0 >= N) return;

    int nn[U]; bool vv[U];
    #pragma unroll
    for (int u = 0; u < U; ++u) { vv[u] = (n0+u) < N; nn[u] = vv[u] ? (n0+u) : n0; }

    float HAMON[U],tanlat[U],SCF[U],PXTEMP[U],mfa[U],mfb[U],mrosk[U],MBASE[U],TIPM[U];
    float PLWHC[U],NMF[U],DAYGM[U],UZTWM[U],iUZTWM[U],UZFWM[U],ku[U],pm[U],ZPERC[U];
    float REXP[U],PFREE[U],LZTWM[U],LZFPM[U],LZFSM[U],kp[U],ks[U],iside[U];
    float PCTIM[U],ADIMP[U],pfac[U],itwm[U],twm[U],ilzmax[U];
    float wA[U]; int bi[U];

    const float dtq = 1.0f / (float)N_INC;
    #pragma unroll
    for (int u = 0; u < U; ++u) {
        const int n = nn[u];
        HAMON[u]=P[ 0*N+n]; SCF[u]  =P[ 1*N+n]; PXTEMP[u]=P[ 2*N+n];
        float MFMAX=P[ 3*N+n], MFMIN=P[ 4*N+n];
        mfa[u]=0.5f*(MFMAX+MFMIN); mfb[u]=0.5f*(MFMAX-MFMIN);
        mrosk[u]=P[ 5*N+n]*__expf(-elev_m[n]*(1.0f/8434.0f))*0.0125f;
        MBASE[u]=P[ 6*N+n]; TIPM[u]=P[ 7*N+n]; PLWHC[u]=P[ 8*N+n];
        NMF[u]  =P[ 9*N+n]; DAYGM[u]=P[10*N+n];
        UZTWM[u]=P[11*N+n]; iUZTWM[u]=frcp(UZTWM[u]);
        UZFWM[u]=P[12*N+n];
        LZTWM[u]=P[13*N+n]; LZFPM[u]=P[14*N+n]; LZFSM[u]=P[15*N+n];
        ku[u]   =P[16*N+n]*dtq;
        float LZPK=P[17*N+n], LZSK=P[18*N+n];
        kp[u]=LZPK*dtq; ks[u]=LZSK*dtq;
        pm[u]=(LZFPM[u]*LZPK + LZFSM[u]*LZSK)*dtq*frcp(UZFWM[u]);
        ZPERC[u]=P[19*N+n]; REXP[u]=P[20*N+n]; PFREE[u]=P[21*N+n];
        PCTIM[u]=P[22*N+n]; ADIMP[u]=P[23*N+n];
        iside[u]=frcp(1.0f + P[25*N+n]);
        pfac[u]=(1.0f - PCTIM[u] - ADIMP[u])*dtq;
        twm[u]=UZTWM[u]+LZTWM[u]; itwm[u]=frcp(twm[u]);
        ilzmax[u]=frcp(LZTWM[u]+LZFPM[u]+LZFSM[u]);
        tanlat[u]=__tanf(lat_rad[n]);
        wA[u]=area_w[n]; bi[u]=basin_idx[n];
    }

    // fallback-tier routing state
    float uh[U][UH_LEN], hist[U][UH_LEN-1];
    if (!SPLIT) {
        #pragma unroll
        for (int u = 0; u < U; ++u) {
            float UH_N = P[28*N+nn[u]], UH_TAU = P[29*N+nn[u]];
            float s = 0.f, inv_tau = frcp(UH_TAU);
            #pragma unroll
            for (int l = 0; l < UH_LEN; ++l) {
                uh[u][l] = __expf((UH_N - 1.0f)*LOGT[l] - (float)(l+1)*inv_tau);
                s += uh[u][l];
            }
            float is = frcp(s);
            #pragma unroll
            for (int l = 0; l < UH_LEN; ++l) uh[u][l] *= is;
            #pragma unroll
            for (int l = 0; l < UH_LEN-1; ++l) hist[u][l] = 0.f;
        }
    }

    float wi[U], wq[U], ati[U], uztwc[U], uzfwc[U], lztwc[U], lzfpc[U], lzfsc[U], adimc[U];
    #pragma unroll
    for (int u = 0; u < U; ++u) {
        wi[u]=0.f; wq[u]=0.f; ati[u]=0.f;
        uztwc[u]=0.5f*UZTWM[u]; uzfwc[u]=0.5f*UZFWM[u]; lztwc[u]=0.5f*LZTWM[u];
        lzfpc[u]=0.5f*LZFPM[u]; lzfsc[u]=0.5f*LZFSM[u]; adimc[u]=0.5f*twm[u];
    }

    float* q_gauge = out;
    float* q_base  = out + (size_t)B*T;
    float* q_unit  = out + (size_t)2*B*T;

    // prime t=0
    float pr_c[U], ta_c[U], pet_c[U], mf_c[U];
    #pragma unroll
    for (int u = 0; u < U; ++u) {
        pr_c[u] = prcp[(size_t)nn[u]*T];
        ta_c[u] = tavg[(size_t)nn[u]*T];
        float dy = (float)doy[(size_t)nn[u]*T];
        float decl = 0.4093f*__sinf(TWO_PI_365*dy - 1.405f);
        float cosw = fminf(fmaxf(-tanlat[u]*__tanf(decl), -0.9999f), 0.9999f);
        pet_c[u] = fmaxf(HAMON[u]*29.8f*(acosf(cosw)*H24_PI)
                         *0.6108f*__expf(17.27f*ta_c[u]*frcp(ta_c[u] + 237.3f))
                         *frcp(ta_c[u] + 273.2f), 0.0f);
        mf_c[u] = mfa[u] + mfb[u]*__sinf(TWO_PI_366*dy);
    }

    for (int t = 0; t < T; ++t) {
        const int tn = min(t + 1, T - 1);
        float pr_n[U], ta_n[U], dy_n[U];
        #pragma unroll
        for (int u = 0; u < U; ++u) {
            pr_n[u] = prcp[(size_t)nn[u]*T + tn];
            ta_n[u] = tavg[(size_t)nn[u]*T + tn];
            dy_n[u] = (float)doy[(size_t)nn[u]*T + tn];
        }

        #pragma unroll
        for (int u = 0; u < U; ++u) {
            const float pr = pr_c[u], ta = ta_c[u], pet = pet_c[u], mf = mf_c[u];

            // --- Snow17 ---
            bool is_snow = (ta <= PXTEMP[u]);
            float ps    = is_snow ? pr*SCF[u] : 0.0f;
            float prain = is_snow ? 0.0f : pr;
            wi[u] += ps;
            ati[u] += TIPM[u]*(fminf(ta, 0.0f) - ati[u]);
            float mros = mrosk[u]*fmaxf(ta, 0.0f)*((!is_snow && wi[u] > 0.0f) ? prain : 0.0f);
            float melt = fminf(fmaxf(mf*fmaxf(ta - MBASE[u], 0.0f) + mros
                                     - NMF[u]*fmaxf(-ati[u], 0.0f), 0.0f), wi[u]);
            wi[u] -= melt;
            float gm = fminf(DAYGM[u], wi[u]);
            wi[u] -= gm;
            float rop   = (wi[u] > 0.0f) ? prain : 0.0f;
            float rfree = prain - rop;
            wq[u] += melt + rop;
            float outq = fmaxf(wq[u] - PLWHC[u]*wi[u], 0.0f);
            wq[u] -= outq;
            float eff = outq + gm + rfree;

            // --- SAC-SMA ---
            float e1 = fminf(pet*uztwc[u]*iUZTWM[u], uztwc[u]);
            uztwc[u] -= e1;
            float red = pet - e1;
            float e2 = fminf(red, uzfwc[u]);
            uzfwc[u] -= e2; red -= e2;
            float e3 = fminf(red*lztwc[u]*itwm[u], lztwc[u]);
            lztwc[u] -= e3;
            float roimp  = eff*PCTIM[u];
            float padimp = eff*ADIMP[u];
            adimc[u] += padimp;
            float ratio = fminf(fmaxf(adimc[u]*itwm[u], 0.0f), 1.0f);
            float adsur = padimp*ratio*ratio;
            adimc[u] = fminf(adimc[u] - adsur, twm[u]);
            float surf = roimp + adsur;
            float base = 0.0f;
            float pinc = eff*pfac[u];
            #pragma unroll
            for (int inc = 0; inc < N_INC; ++inc) {
                float bfp = lzfpc[u]*kp[u];
                float bfs = lzfsc[u]*ks[u];
                lzfpc[u] -= bfp; lzfsc[u] -= bfs;
                base += (bfp + bfs)*iside[u];
                float qif = uzfwc[u]*ku[u];
                uzfwc[u] -= qif; surf += qif;
                float lz_def = (LZTWM[u]-lztwc[u]) + (LZFPM[u]-lzfpc[u]) + (LZFSM[u]-lzfsc[u]);
                float defr = fminf(fmaxf(lz_def*ilzmax[u], 1e-6f), 1.0f);
                float perc = pm[u]*fmaf(ZPERC[u], __expf(REXP[u]*__logf(defr)), 1.0f)*uzfwc[u];
                perc = fminf(fminf(perc, uzfwc[u]), fmaxf(lz_def, 0.0f));
                uzfwc[u] -= perc;
                float pfree = perc*PFREE[u];
                lztwc[u] += perc - pfree;
                float ex = fmaxf(lztwc[u] - LZTWM[u], 0.0f);
                lztwc[u] -= ex; pfree += ex;
                float dp  = fmaxf(LZFPM[u] - lzfpc[u], 0.0f);
                float dsx = fmaxf(LZFSM[u] - lzfsc[u], 0.0f);
                float fr  = dp*frcp(fmaxf(dp + dsx, 1e-6f));
                lzfpc[u] += pfree*fr;
                lzfsc[u] += pfree*(1.0f - fr);
                float exq = fmaxf(lzfpc[u] - LZFPM[u], 0.0f);
                lzfpc[u] -= exq; lzfsc[u] += exq;
                float exs = fmaxf(lzfsc[u] - LZFSM[u], 0.0f);
                lzfsc[u] -= exs; surf += exs;
                uztwc[u] += pinc;
                float exu = fmaxf(uztwc[u] - UZTWM[u], 0.0f);
                uztwc[u] -= exu; uzfwc[u] += exu;
                float exf = fmaxf(uzfwc[u] - UZFWM[u], 0.0f);
                uzfwc[u] -= exf; surf += exf;
            }

            if (SPLIT) {
                if (vv[u]) {
                    surfA[(size_t)nn[u]*T + t] = surf;
                    baseA[(size_t)nn[u]*T + t] = base;
                }
            } else {
                float qv = uh[u][0]*surf;
                #pragma unroll
                for (int l = 1; l < UH_LEN; ++l) qv = fmaf(uh[u][l], hist[u][l-1], qv);
                #pragma unroll
                for (int l = UH_LEN-2; l >= 1; --l) hist[u][l] = hist[u][l-1];
                hist[u][0] = surf;
                qv += base;
                if (vv[u]) {
                    q_unit[(size_t)nn[u]*T + t] = qv;
                    atomicAdd(&q_gauge[(size_t)bi[u]*T + t], qv*wA[u]);
                    atomicAdd(&q_base [(size_t)bi[u]*T + t], base*wA[u]);
                }
            }
        }

        // ahead-compute pet/mf for t+1 (independent; fills stall slots)
        #pragma unroll
        for (int u = 0; u < U; ++u) {
            float decl = 0.4093f*__sinf(TWO_PI_365*dy_n[u] - 1.405f);
            float cosw = fminf(fmaxf(-tanlat[u]*__tanf(decl), -0.9999f), 0.9999f);
            pet_c[u] = fmaxf(HAMON[u]*29.8f*(acosf(cosw)*H24_PI)
                             *0.6108f*__expf(17.27f*ta_n[u]*frcp(ta_n[u] + 237.3f))
                             *frcp(ta_n[u] + 273.2f), 0.0f);
            mf_c[u] = mfa[u] + mfb[u]*__sinf(TWO_PI_366*dy_n[u]);
            pr_c[u] = pr_n[u]; ta_c[u] = ta_n[u];
        }
    }
}

// ---------------------------------------------------------------------------
// Routing + gauge segment-sum: fully parallel over (n, t).
// ---------------------------------------------------------------------------
__global__ __launch_bounds__(256) void route_kernel(
    const float* __restrict__ surfA, const float* __restrict__ baseA,
    const float* __restrict__ P, const float* __restrict__ area_w,
    const int* __restrict__ basin_idx,
    float* __restrict__ out, int N, int T, int B)
{
    __shared__ float uh_sh[UH_LEN];
    __shared__ float wA_sh;
    __shared__ int   bi_sh;

    const int n = blockIdx.y;
    const int t = blockIdx.x*256 + threadIdx.x;

    if (threadIdx.x == 0) {
        float UH_N = P[28*N + n], UH_TAU = P[29*N + n];
        float inv_tau = frcp(UH_TAU);
        float tmp[UH_LEN], s = 0.f;
        #pragma unroll
        for (int l = 0; l < UH_LEN; ++l) {
            tmp[l] = __expf((UH_N - 1.0f)*LOGT[l] - (float)(l+1)*inv_tau);
            s += tmp[l];
        }
        float is = frcp(s);
        #pragma unroll
        for (int l = 0; l < UH_LEN; ++l) uh_sh[l] = tmp[l]*is;
        wA_sh = area_w[n];
        bi_sh = basin_idx[n];
    }
    __syncthreads();
    if (t >= T) return;

    const float base = baseA[(size_t)n*T + t];
    float acc = 0.f;
    #pragma unroll
    for (int l = 0; l < UH_LEN; ++l) {
        int tt = t - l;
        if (tt >= 0) acc = fmaf(uh_sh[l], surfA[(size_t)n*T + tt], acc);
    }
    const float qv = acc + base;

    float* q_gauge = out;
    float* q_base  = out + (size_t)B*T;
    float* q_unit  = out + (size_t)2*B*T;

    q_unit[(size_t)n*T + t] = qv;
    atomicAdd(&q_gauge[(size_t)bi_sh*T + t], qv*wA_sh);
    atomicAdd(&q_base [(size_t)bi_sh*T + t], base*wA_sh);
}

extern "C" void kernel_launch(void* const* d_in, const int* in_sizes, int n_in,
                              void* d_out, int out_size, void* d_ws, size_t ws_size,
                              hipStream_t stream) {
    const float* x_dyn    = (const float*)d_in[0];
    const float* x_static = (const float*)d_in[1];
    const float* prcp     = (const float*)d_in[2];
    const float* tavg     = (const float*)d_in[3];
    const int*   doy      = (const int*)  d_in[4];
    const float* elev_m   = (const float*)d_in[5];
    const float* lat_rad  = (const float*)d_in[6];
    const float* area_w   = (const float*)d_in[7];
    const int*   basin_ix = (const int*)  d_in[8];
    const float* Wih      = (const float*)d_in[10];
    const float* Whh      = (const float*)d_in[11];
    const float* b_lstm   = (const float*)d_in[12];
    const float* Ws       = (const float*)d_in[13];
    const float* bs       = (const float*)d_in[14];
    const float* Wout     = (const float*)d_in[15];
    const float* bout     = (const float*)d_in[16];

    const int N = in_sizes[7];
    const int T = in_sizes[2] / N;
    const int DSTAT = in_sizes[1] / N;
    const int NT = N * T;
    const int B = (out_size - NT) / (2 * T);

    float* params = (float*)d_ws;                       // [30][N]
    float* surfA  = params + 30*(size_t)N;              // [N][T]
    float* baseA  = surfA + (size_t)NT;                 // [N][T]
    const size_t need = (30*(size_t)N + 2*(size_t)NT) * sizeof(float);
    const bool split = (ws_size >= need);
    float* out = (float*)d_out;

    const int zc = 2 * B * T;
    zero_kernel<<<(zc + 255)/256, 256, 0, stream>>>(out, zc);

    const int blocks_lstm = (N + 31) / 32;
    lstm_kernel<<<blocks_lstm, 256, 0, stream>>>(x_dyn, x_static, Wih, Whh, b_lstm,
                                                 Ws, bs, Wout, bout, params, N, T, DSTAT);

    if (split) {
        const int nthr = (N + 3) / 4;
        const int pblocks = (nthr + 63) / 64;
        physics_kernel<4, true><<<pblocks, 64, 0, stream>>>(prcp, tavg, doy, elev_m, lat_rad,
                                                            area_w, basin_ix, params,
                                                            surfA, baseA, out, N, T, B);
        dim3 rg((T + 255)/256, N);
        route_kernel<<<rg, 256, 0, stream>>>(surfA, baseA, params, area_w, basin_ix,
                                             out, N, T, B);
    } else {
        const int pblocks = (N + 63) / 64;
        physics_kernel<1, false><<<pblocks, 64, 0, stream>>>(prcp, tavg, doy, elev_m, lat_rad,
                                                             area_w, basin_ix, params,
                                                             surfA, baseA, out, N, T, B);
    }
}

// Round 6
// 1212.654 us; speedup vs baseline: 2.6092x; 2.6092x over previous
//
#include <hip/hip_runtime.h>
#include <math.h>

#define HID 64
#define UH_LEN 15
#define N_INC 4

#define TWO_PI_365 0.0172142063f
#define TWO_PI_366 0.0171671554f
#define H24_PI     7.63943727f

typedef short short8 __attribute__((ext_vector_type(8)));
typedef float f32x4  __attribute__((ext_vector_type(4)));

__device__ __forceinline__ float frcp(float x){ return __builtin_amdgcn_rcpf(x); }
__device__ __forceinline__ float sigf(float x){ return frcp(1.0f + __expf(-x)); }
__device__ __forceinline__ float tanhfast(float x){ return 1.0f - 2.0f*frcp(__expf(2.0f*x)+1.0f); }

__device__ __forceinline__ unsigned short f2bf(float f){
    unsigned int u = __float_as_uint(f);
    u += 0x7FFF + ((u >> 16) & 1);
    return (unsigned short)(u >> 16);
}
__device__ __forceinline__ float bf2f(unsigned short h){
    return __uint_as_float(((unsigned int)h) << 16);
}

__device__ const float PLO[30] = {0.5f,0.7f,-2.0f,0.5f,0.05f,0.03f,0.0f,0.1f,0.02f,0.05f,0.0f,
                                  10.0f,5.0f,10.0f,10.0f,5.0f,0.1f,0.001f,0.01f,5.0f,1.0f,0.0f,
                                  0.0f,0.0f,0.0f,0.0f,0.0f,0.0f,1.0f,0.5f};
__device__ const float PHI[30] = {2.0f,1.4f,2.0f,2.0f,0.49f,0.19f,1.0f,1.0f,0.3f,0.5f,0.3f,
                                  300.0f,150.0f,500.0f,1000.0f,400.0f,0.75f,0.05f,0.35f,350.0f,5.0f,0.8f,
                                  0.1f,0.4f,0.2f,0.5f,0.4f,1.0f,6.0f,5.0f};
__device__ const float LOGT[15] = {0.0f,0.69314718f,1.09861229f,1.38629436f,1.60943791f,
                                   1.79175947f,1.94591015f,2.07944154f,2.19722458f,2.30258509f,
                                   2.39789527f,2.48490665f,2.56494936f,2.63905733f,2.70805020f};

__global__ void zero_kernel(float* __restrict__ p, int cnt){
    int i = blockIdx.x*256 + threadIdx.x;
    if (i < cnt) p[i] = 0.0f;
}

// ---------------------------------------------------------------------------
// MFMA LSTM (r4 version, M=16 — measured ~480 us; M=32 regressed, reverted).
// ---------------------------------------------------------------------------
__global__ __launch_bounds__(256, 1) void lstm_kernel(
    const float* __restrict__ x_dyn, const float* __restrict__ x_static,
    const float* __restrict__ Wih, const float* __restrict__ Whh,
    const float* __restrict__ b_lstm, const float* __restrict__ Ws,
    const float* __restrict__ bs, const float* __restrict__ Wout,
    const float* __restrict__ bout, float* __restrict__ params,
    int N, int T, int DSTAT)
{
    __shared__ unsigned short h_lds[2][16*64];
    __shared__ float s_sh[16*64];

    const int tid = threadIdx.x;
    const int wv  = tid >> 6;
    const int ln  = tid & 63;
    const int q   = ln >> 4;
    const int r16 = ln & 15;
    const int u0  = blockIdx.x * 16;

    short8 wf[4][3];
    float  bias[4];
    #pragma unroll
    for (int g = 0; g < 4; ++g) {
        const int n = 64*g + 16*wv + r16;
        bias[g] = b_lstm[n];
        #pragma unroll
        for (int kb = 0; kb < 3; ++kb) {
            short8 w;
            #pragma unroll
            for (int e = 0; e < 8; ++e) {
                int k = 32*kb + 8*q + e;
                float v = 0.0f;
                if (k < 64)      v = Whh[n*64 + k];
                else if (k < 72) v = Wih[n*8 + (k - 64)];
                w[e] = (short)f2bf(v);
            }
            wf[g][kb] = w;
        }
    }

    for (int i = tid; i < 2*16*64; i += 256) ((unsigned short*)h_lds)[i] = 0;
    __syncthreads();

    float c[4] = {0.f, 0.f, 0.f, 0.f};

    const int ux = min(u0 + r16, N-1);
    float xf[8];
    if (q == 0) {
        const float* p = x_dyn + ((size_t)ux * T) * 8;
        #pragma unroll
        for (int e = 0; e < 8; ++e) xf[e] = p[e];
    }

    const int jj   = 16*wv + r16;
    const int swz0 = (q       ^ (r16 & 7)) << 3;
    const int swz1 = ((q + 4) ^ (r16 & 7)) << 3;

    for (int t = 0; t < T; ++t) {
        short8 a2;
        #pragma unroll
        for (int e = 0; e < 8; ++e) a2[e] = (q == 0) ? (short)f2bf(xf[e]) : (short)0;

        const int rb = t & 1;
        short8 a0 = *(const short8*)&h_lds[rb][r16*64 + swz0];
        short8 a1 = *(const short8*)&h_lds[rb][r16*64 + swz1];

        if (q == 0 && t + 1 < T) {
            const float* p = x_dyn + ((size_t)ux * T + (t+1)) * 8;
            #pragma unroll
            for (int e = 0; e < 8; ++e) xf[e] = p[e];
        }

        f32x4 acc[4];
        #pragma unroll
        for (int g = 0; g < 4; ++g) {
            f32x4 a; a[0]=bias[g]; a[1]=bias[g]; a[2]=bias[g]; a[3]=bias[g];
            a = __builtin_amdgcn_mfma_f32_16x16x32_bf16(a2, wf[g][2], a, 0, 0, 0);
            a = __builtin_amdgcn_mfma_f32_16x16x32_bf16(a0, wf[g][0], a, 0, 0, 0);
            a = __builtin_amdgcn_mfma_f32_16x16x32_bf16(a1, wf[g][1], a, 0, 0, 0);
            acc[g] = a;
        }

        const int wb = rb ^ 1;
        #pragma unroll
        for (int r = 0; r < 4; ++r) {
            float iv = sigf(acc[0][r]);
            float fv = sigf(acc[1][r]);
            float gv = tanhfast(acc[2][r]);
            float ov = sigf(acc[3][r]);
            c[r] = fv*c[r] + iv*gv;
            float hv = ov*tanhfast(c[r]);
            int u = 4*q + r;
            h_lds[wb][u*64 + (((jj>>3) ^ (u&7))<<3) + (jj&7)] = f2bf(hv);
        }
        __syncthreads();
    }

    const int fb = T & 1;
    for (int uu = 0; uu < 4; ++uu) {
        int ul = wv*4 + uu;
        int u  = min(u0 + ul, N-1);
        float a = bs[ln];
        for (int k = 0; k < DSTAT; ++k)
            a = fmaf(x_static[(size_t)u*DSTAT + k], Ws[ln*DSTAT + k], a);
        s_sh[ul*64 + ln] = tanhfast(a);
    }
    if (ln < 30) {
        for (int uu = 0; uu < 4; ++uu) {
            int ul = wv*4 + uu;
            int unit = u0 + ul;
            if (unit < N) {
                float raw = bout[ln];
                #pragma unroll 8
                for (int m = 0; m < 64; ++m) {
                    float hm = bf2f(h_lds[fb][ul*64 + (((m>>3) ^ (ul&7))<<3) + (m&7)]);
                    float sm = s_sh[ul*64 + m];
                    raw = fmaf(hm, Wout[ln*128 + m],      raw);
                    raw = fmaf(sm, Wout[ln*128 + 64 + m], raw);
                }
                float g = sigf(raw);
                params[ln*N + unit] = PLO[ln] + g*(PHI[ln] - PLO[ln]);
            }
        }
    }
}

// ---------------------------------------------------------------------------
// Pack kernel (fully parallel, after LSTM): per (n,t) write float4
// (prcp, tavg, PET, melt_factor). Removes ALL transcendentals and 2 of 3
// load streams from the serial physics chain.
// ---------------------------------------------------------------------------
__global__ __launch_bounds__(256) void pack_kernel(
    const float* __restrict__ prcp, const float* __restrict__ tavg,
    const int* __restrict__ doy, const float* __restrict__ lat_rad,
    const float* __restrict__ P,
    float4* __restrict__ pack, int N, int T)
{
    const int n = blockIdx.y;
    const int t = blockIdx.x*256 + threadIdx.x;
    if (t >= T) return;
    const float pr = prcp[(size_t)n*T + t];
    const float ta = tavg[(size_t)n*T + t];
    const float dy = (float)doy[(size_t)n*T + t];
    const float tanlat = __tanf(lat_rad[n]);
    const float HAMON  = P[n];
    const float MFMAX  = P[3*N + n], MFMIN = P[4*N + n];
    float decl  = 0.4093f*__sinf(TWO_PI_365*dy - 1.405f);
    float cosw  = fminf(fmaxf(-tanlat*__tanf(decl), -0.9999f), 0.9999f);
    float daylen= acosf(cosw)*H24_PI;
    float esat  = 0.6108f*__expf(17.27f*ta*frcp(ta + 237.3f));
    float pet   = fmaxf(HAMON*29.8f*daylen*esat*frcp(ta + 273.2f), 0.0f);
    float mf    = 0.5f*(MFMAX + MFMIN) + 0.5f*(MFMAX - MFMIN)*__sinf(TWO_PI_366*dy);
    pack[(size_t)n*T + t] = make_float4(pr, ta, pet, mf);
}

// ---------------------------------------------------------------------------
// Physics serial chain, U=1. PACKED: one float4 load/t (2-deep prefetch),
// one float2 store/t; zero transcendentals in the loop.
// ---------------------------------------------------------------------------
template<bool PACKED, bool SPLIT>
__global__ __launch_bounds__(64, 1) void physics_kernel(
    const float* __restrict__ prcp, const float* __restrict__ tavg,
    const int*   __restrict__ doy,  const float* __restrict__ elev_m,
    const float* __restrict__ lat_rad, const float* __restrict__ area_w,
    const int*   __restrict__ basin_idx, const float* __restrict__ P,
    const float4* __restrict__ pack, float2* __restrict__ sbA,
    float* __restrict__ surfA, float* __restrict__ baseA,
    float* __restrict__ out, int N, int T, int B)
{
    int n = blockIdx.x*64 + threadIdx.x;
    if (n >= N) return;

    const float HAMON = P[ 0*N+n], SCF   = P[ 1*N+n], PXTEMP= P[ 2*N+n];
    const float MFMAX = P[ 3*N+n], MFMIN = P[ 4*N+n];
    const float MBASE = P[ 6*N+n], TIPM  = P[ 7*N+n], PLWHC = P[ 8*N+n];
    const float NMF   = P[ 9*N+n], DAYGM = P[10*N+n];
    const float UZTWM = P[11*N+n], UZFWM = P[12*N+n], LZTWM = P[13*N+n];
    const float LZFPM = P[14*N+n], LZFSM = P[15*N+n], UZK   = P[16*N+n];
    const float LZPK  = P[17*N+n], LZSK  = P[18*N+n], ZPERC = P[19*N+n];
    const float REXP  = P[20*N+n], PFREE = P[21*N+n], PCTIM = P[22*N+n];
    const float ADIMP = P[23*N+n], SIDE  = P[25*N+n];
    const float UH_N  = P[28*N+n], UH_TAU= P[29*N+n];

    const float mrosk  = P[5*N+n]*__expf(-elev_m[n]*(1.0f/8434.0f))*0.0125f;
    const float tanlat = __tanf(lat_rad[n]);
    const float wA     = area_w[n];
    const int   bi     = basin_idx[n];
    const float mfa = 0.5f*(MFMAX + MFMIN), mfb = 0.5f*(MFMAX - MFMIN);

    float uh[UH_LEN];
    float hist[UH_LEN-1];
    if (!SPLIT) {
        float uhs = 0.0f;
        const float inv_tau = frcp(UH_TAU);
        #pragma unroll
        for (int l = 0; l < UH_LEN; ++l) {
            uh[l] = __expf((UH_N - 1.0f)*LOGT[l] - (float)(l+1)*inv_tau);
            uhs += uh[l];
        }
        float inv_uhs = frcp(uhs);
        #pragma unroll
        for (int l = 0; l < UH_LEN; ++l) uh[l] *= inv_uhs;
        #pragma unroll
        for (int l = 0; l < UH_LEN-1; ++l) hist[l] = 0.0f;
    }

    const float dtq       = 1.0f / (float)N_INC;
    const float kp        = LZPK*dtq, ks = LZSK*dtq, ku = UZK*dtq;
    const float twm_sum   = UZTWM + LZTWM;
    const float inv_uztwm = frcp(UZTWM);
    const float inv_twm   = frcp(twm_sum);
    const float inv_lzmax = frcp(LZTWM + LZFPM + LZFSM);
    const float inv_side  = frcp(1.0f + SIDE);
    const float pinc_fac  = (1.0f - PCTIM - ADIMP)*dtq;
    const float pm        = (LZFPM*LZPK + LZFSM*LZSK)*dtq*frcp(UZFWM);

    float wi = 0.0f, wq = 0.0f, ati = 0.0f;
    float uztwc = 0.5f*UZTWM, uzfwc = 0.5f*UZFWM, lztwc = 0.5f*LZTWM;
    float lzfpc = 0.5f*LZFPM, lzfsc = 0.5f*LZFSM, adimc = 0.5f*twm_sum;

    float* q_gauge = out;
    float* q_base  = out + (size_t)B*T;
    float* q_unit  = out + (size_t)2*B*T;

    // packed-path pointers / prefetch state
    const float4* pk = PACKED ? (pack + (size_t)n*T) : nullptr;
    float2*       sb = PACKED ? (sbA  + (size_t)n*T) : nullptr;
    float4 cur, nx1;
    float pr_c, ta_c, pet_c, mf_c;   // non-packed path state
    if (PACKED) {
        cur = pk[0];
        nx1 = pk[T > 1 ? 1 : 0];
    } else {
        pr_c = prcp[(size_t)n*T];
        ta_c = tavg[(size_t)n*T];
        float dy = (float)doy[(size_t)n*T];
        float decl = 0.4093f*__sinf(TWO_PI_365*dy - 1.405f);
        float cosw = fminf(fmaxf(-tanlat*__tanf(decl), -0.9999f), 0.9999f);
        pet_c = fmaxf(HAMON*29.8f*(acosf(cosw)*H24_PI)
                      *0.6108f*__expf(17.27f*ta_c*frcp(ta_c + 237.3f))
                      *frcp(ta_c + 273.2f), 0.0f);
        mf_c  = mfa + mfb*__sinf(TWO_PI_366*dy);
    }

    for (int t = 0; t < T; ++t) {
        float pr, ta, pet, mf;
        float4 nx2;
        float pr_n, ta_n, dy_n;
        if (PACKED) {
            nx2 = pk[min(t + 2, T - 1)];   // issue early; consumed 2 iters later
            pr = cur.x; ta = cur.y; pet = cur.z; mf = cur.w;
        } else {
            const int tn = min(t + 1, T - 1);
            pr_n = prcp[(size_t)n*T + tn];
            ta_n = tavg[(size_t)n*T + tn];
            dy_n = (float)doy[(size_t)n*T + tn];
            pr = pr_c; ta = ta_c; pet = pet_c; mf = mf_c;
        }

        // --- Snow17 ---
        bool is_snow = (ta <= PXTEMP);
        float ps    = is_snow ? pr*SCF : 0.0f;
        float prain = is_snow ? 0.0f   : pr;
        wi += ps;
        ati += TIPM*(fminf(ta, 0.0f) - ati);
        float mros = mrosk*fmaxf(ta, 0.0f)*((!is_snow && wi > 0.0f) ? prain : 0.0f);
        float melt = fminf(fmaxf(mf*fmaxf(ta - MBASE, 0.0f) + mros - NMF*fmaxf(-ati, 0.0f), 0.0f), wi);
        wi -= melt;
        float gm = fminf(DAYGM, wi);
        wi -= gm;
        float rop   = (wi > 0.0f) ? prain : 0.0f;
        float rfree = prain - rop;
        wq += melt + rop;
        float outq = fmaxf(wq - PLWHC*wi, 0.0f);
        wq -= outq;
        float eff = outq + gm + rfree;

        // --- SAC-SMA ---
        float e1 = fminf(pet*uztwc*inv_uztwm, uztwc);
        uztwc -= e1;
        float red = pet - e1;
        float e2 = fminf(red, uzfwc);
        uzfwc -= e2; red -= e2;
        float e3 = fminf(red*lztwc*inv_twm, lztwc);
        lztwc -= e3;
        float roimp  = eff*PCTIM;
        float padimp = eff*ADIMP;
        adimc += padimp;
        float ratio = fminf(fmaxf(adimc*inv_twm, 0.0f), 1.0f);
        float adsur = padimp*ratio*ratio;
        adimc = fminf(adimc - adsur, twm_sum);
        float surf = roimp + adsur;
        float base = 0.0f;
        float pinc = eff*pinc_fac;
        #pragma unroll
        for (int inc = 0; inc < N_INC; ++inc) {
            float bfp = lzfpc*kp;
            float bfs = lzfsc*ks;
            lzfpc -= bfp; lzfsc -= bfs;
            base += (bfp + bfs)*inv_side;
            float qif = uzfwc*ku;
            uzfwc -= qif; surf += qif;
            float lz_def = (LZTWM - lztwc) + (LZFPM - lzfpc) + (LZFSM - lzfsc);
            float defr = fminf(fmaxf(lz_def*inv_lzmax, 1e-6f), 1.0f);
            float perc = pm*fmaf(ZPERC, __expf(REXP*__logf(defr)), 1.0f)*uzfwc;
            perc = fminf(fminf(perc, uzfwc), fmaxf(lz_def, 0.0f));
            uzfwc -= perc;
            float pfree = perc*PFREE;
            lztwc += perc - pfree;
            float ex = fmaxf(lztwc - LZTWM, 0.0f);
            lztwc -= ex; pfree += ex;
            float dp  = fmaxf(LZFPM - lzfpc, 0.0f);
            float dsx = fmaxf(LZFSM - lzfsc, 0.0f);
            float fr  = dp*frcp(fmaxf(dp + dsx, 1e-6f));
            lzfpc += pfree*fr;
            lzfsc += pfree*(1.0f - fr);
            float exq = fmaxf(lzfpc - LZFPM, 0.0f);
            lzfpc -= exq; lzfsc += exq;
            float exs = fmaxf(lzfsc - LZFSM, 0.0f);
            lzfsc -= exs; surf += exs;
            uztwc += pinc;
            float exu = fmaxf(uztwc - UZTWM, 0.0f);
            uztwc -= exu; uzfwc += exu;
            float exf = fmaxf(uzfwc - UZFWM, 0.0f);
            uzfwc -= exf; surf += exf;
        }

        if (PACKED) {
            sb[t] = make_float2(surf, base);
            cur = nx1; nx1 = nx2;
        } else if (SPLIT) {
            surfA[(size_t)n*T + t] = surf;
            baseA[(size_t)n*T + t] = base;
        } else {
            float qv = uh[0]*surf;
            #pragma unroll
            for (int l = 1; l < UH_LEN; ++l) qv = fmaf(uh[l], hist[l-1], qv);
            #pragma unroll
            for (int l = UH_LEN-2; l >= 1; --l) hist[l] = hist[l-1];
            hist[0] = surf;
            qv += base;
            q_unit[(size_t)n*T + t] = qv;
            atomicAdd(&q_gauge[(size_t)bi*T + t], qv*wA);
            atomicAdd(&q_base [(size_t)bi*T + t], base*wA);
        }

        if (!PACKED) {
            // ahead-compute pet/mf for t+1 (tier-B fallback path)
            float decl = 0.4093f*__sinf(TWO_PI_365*dy_n - 1.405f);
            float cosw = fminf(fmaxf(-tanlat*__tanf(decl), -0.9999f), 0.9999f);
            pet_c = fmaxf(HAMON*29.8f*(acosf(cosw)*H24_PI)
                          *0.6108f*__expf(17.27f*ta_n*frcp(ta_n + 237.3f))
                          *frcp(ta_n + 273.2f), 0.0f);
            mf_c = mfa + mfb*__sinf(TWO_PI_366*dy_n);
            pr_c = pr_n; ta_c = ta_n;
        }
    }
}

// ---------------------------------------------------------------------------
// Routing + gauge segment-sum: fully parallel over (n, t).
// ---------------------------------------------------------------------------
template<bool PACKED>
__global__ __launch_bounds__(256) void route_kernel(
    const float2* __restrict__ sbA,
    const float* __restrict__ surfA, const float* __restrict__ baseA,
    const float* __restrict__ P, const float* __restrict__ area_w,
    const int* __restrict__ basin_idx,
    float* __restrict__ out, int N, int T, int B)
{
    __shared__ float uh_sh[UH_LEN];
    __shared__ float wA_sh;
    __shared__ int   bi_sh;

    const int n = blockIdx.y;
    const int t = blockIdx.x*256 + threadIdx.x;

    if (threadIdx.x == 0) {
        float UH_N = P[28*N + n], UH_TAU = P[29*N + n];
        float inv_tau = frcp(UH_TAU);
        float tmp[UH_LEN], s = 0.f;
        #pragma unroll
        for (int l = 0; l < UH_LEN; ++l) {
            tmp[l] = __expf((UH_N - 1.0f)*LOGT[l] - (float)(l+1)*inv_tau);
            s += tmp[l];
        }
        float is = frcp(s);
        #pragma unroll
        for (int l = 0; l < UH_LEN; ++l) uh_sh[l] = tmp[l]*is;
        wA_sh = area_w[n];
        bi_sh = basin_idx[n];
    }
    __syncthreads();
    if (t >= T) return;

    float base, acc = 0.f;
    if (PACKED) {
        const float2* sb = sbA + (size_t)n*T;
        base = sb[t].y;
        #pragma unroll
        for (int l = 0; l < UH_LEN; ++l) {
            int tt = t - l;
            if (tt >= 0) acc = fmaf(uh_sh[l], sb[tt].x, acc);
        }
    } else {
        base = baseA[(size_t)n*T + t];
        #pragma unroll
        for (int l = 0; l < UH_LEN; ++l) {
            int tt = t - l;
            if (tt >= 0) acc = fmaf(uh_sh[l], surfA[(size_t)n*T + tt], acc);
        }
    }
    const float qv = acc + base;

    float* q_gauge = out;
    float* q_base  = out + (size_t)B*T;
    float* q_unit  = out + (size_t)2*B*T;

    q_unit[(size_t)n*T + t] = qv;
    atomicAdd(&q_gauge[(size_t)bi_sh*T + t], qv*wA_sh);
    atomicAdd(&q_base [(size_t)bi_sh*T + t], base*wA_sh);
}

extern "C" void kernel_launch(void* const* d_in, const int* in_sizes, int n_in,
                              void* d_out, int out_size, void* d_ws, size_t ws_size,
                              hipStream_t stream) {
    const float* x_dyn    = (const float*)d_in[0];
    const float* x_static = (const float*)d_in[1];
    const float* prcp     = (const float*)d_in[2];
    const float* tavg     = (const float*)d_in[3];
    const int*   doy      = (const int*)  d_in[4];
    const float* elev_m   = (const float*)d_in[5];
    const float* lat_rad  = (const float*)d_in[6];
    const float* area_w   = (const float*)d_in[7];
    const int*   basin_ix = (const int*)  d_in[8];
    const float* Wih      = (const float*)d_in[10];
    const float* Whh      = (const float*)d_in[11];
    const float* b_lstm   = (const float*)d_in[12];
    const float* Ws       = (const float*)d_in[13];
    const float* bs       = (const float*)d_in[14];
    const float* Wout     = (const float*)d_in[15];
    const float* bout     = (const float*)d_in[16];

    const int N = in_sizes[7];
    const int T = in_sizes[2] / N;
    const int DSTAT = in_sizes[1] / N;
    const int NT = N * T;
    const int B = (out_size - NT) / (2 * T);

    float* params = (float*)d_ws;                       // [30][N]
    float* out    = (float*)d_out;

    // Tier A (packed): params + pack(4NT) + sb(2NT)
    const size_t needA = (30*(size_t)N + 6*(size_t)NT) * sizeof(float);
    // Tier B (split, unpacked): params + surf(NT) + base(NT)
    const size_t needB = (30*(size_t)N + 2*(size_t)NT) * sizeof(float);
    const bool tierA = (ws_size >= needA);
    const bool tierB = (!tierA) && (ws_size >= needB);

    float4* pack = (float4*)(params + 30*(size_t)N);
    float2* sbA  = (float2*)(params + 30*(size_t)N + 4*(size_t)NT);
    float*  surfA = params + 30*(size_t)N;
    float*  baseA = surfA + (size_t)NT;

    const int zc = 2 * B * T;
    zero_kernel<<<(zc + 255)/256, 256, 0, stream>>>(out, zc);

    const int blocks_lstm = (N + 15) / 16;
    lstm_kernel<<<blocks_lstm, 256, 0, stream>>>(x_dyn, x_static, Wih, Whh, b_lstm,
                                                 Ws, bs, Wout, bout, params, N, T, DSTAT);

    const int pblocks = (N + 63) / 64;
    if (tierA) {
        dim3 pg((T + 255)/256, N);
        pack_kernel<<<pg, 256, 0, stream>>>(prcp, tavg, doy, lat_rad, params, pack, N, T);
        physics_kernel<true, true><<<pblocks, 64, 0, stream>>>(
            prcp, tavg, doy, elev_m, lat_rad, area_w, basin_ix, params,
            pack, sbA, surfA, baseA, out, N, T, B);
        dim3 rg((T + 255)/256, N);
        route_kernel<true><<<rg, 256, 0, stream>>>(sbA, surfA, baseA, params, area_w,
                                                   basin_ix, out, N, T, B);
    } else if (tierB) {
        physics_kernel<false, true><<<pblocks, 64, 0, stream>>>(
            prcp, tavg, doy, elev_m, lat_rad, area_w, basin_ix, params,
            pack, sbA, surfA, baseA, out, N, T, B);
        dim3 rg((T + 255)/256, N);
        route_kernel<false><<<rg, 256, 0, stream>>>(sbA, surfA, baseA, params, area_w,
                                                    basin_ix, out, N, T, B);
    } else {
        physics_kernel<false, false><<<pblocks, 64, 0, stream>>>(
            prcp, tavg, doy, elev_m, lat_rad, area_w, basin_ix, params,
            pack, sbA, surfA, baseA, out, N, T, B);
    }
}